// Round 2
// baseline (635.934 us; speedup 1.0000x reference)
//
#include <hip/hip_runtime.h>
#include <hip/hip_bf16.h>

#define IN_FEAT 128
#define N_HEADS 4
#define OUT_FEAT 16
#define HF 64  // N_HEADS * OUT_FEAT
#define NEG_SLOPE 0.2f

#define BSHIFT 7                 // 128 nodes per bucket
#define BNODES 128
#define NBUCK_MAX 512            // >= ceil(50000/128)=391
#define NPB 256                  // partition/histogram blocks (shared chunking)

typedef __hip_bfloat16 bf16;
typedef __attribute__((ext_vector_type(8))) short short8;
typedef __attribute__((ext_vector_type(4))) float f32x4;

__device__ inline unsigned short f2b(float f) {
  bf16 b = __float2bfloat16(f);
  return *(unsigned short*)&b;
}
__device__ inline float b2f(unsigned short u) {
  return __uint_as_float((unsigned)u << 16);
}
// Extract bf16 alpha for head sel (0..3) from packed {lo,hi} words.
__device__ inline float alpha_lane(unsigned lo, unsigned hi, unsigned sel) {
  unsigned wd = (sel & 2u) ? hi : lo;
  return __uint_as_float(((wd >> ((sel & 1u) * 16u)) & 0xffffu) << 16);
}

// ---------------------------------------------------------------------------
// Kernel 1: h = x @ W via bf16 MFMA (pure — histogram removed; zero atomics).
// Block = 256 thr = 4 waves = 64 nodes; 16 mfma_f32_16x16x32_bf16 per wave.
// ---------------------------------------------------------------------------
__global__ __launch_bounds__(256) void k_gemm(
    const float* __restrict__ x, const float* __restrict__ W,
    const float* __restrict__ a, unsigned short* __restrict__ h16,
    float* __restrict__ e_src, float* __restrict__ e_dst, int n_nodes) {
  __shared__ unsigned short xs[64][136];
  __shared__ unsigned short wt[64][136];
  __shared__ unsigned short sh[64][68];
  const int t = threadIdx.x;
  const int nb = blockIdx.x * 64;
  const int lane = t & 63;
  const int w = t >> 6;

  const float4* x4 = (const float4*)x;
  for (int i = t; i < 64 * 32; i += 256) {
    int n = i >> 5, k4 = i & 31;
    int gn = nb + n;
    float4 v = (gn < n_nodes) ? x4[(size_t)gn * 32 + k4]
                              : make_float4(0.f, 0.f, 0.f, 0.f);
    ushort4 u;
    u.x = f2b(v.x); u.y = f2b(v.y); u.z = f2b(v.z); u.w = f2b(v.w);
    *(ushort4*)&xs[n][k4 * 4] = u;
  }
  for (int i = t; i < IN_FEAT * HF; i += 256) {
    int k = i >> 6, c = i & 63;
    wt[c][k] = f2b(W[i]);
  }
  __syncthreads();

  const int m = lane & 15;
  const int q = lane >> 4;
  f32x4 acc[4];
#pragma unroll
  for (int nt = 0; nt < 4; ++nt) acc[nt] = (f32x4){0.f, 0.f, 0.f, 0.f};

#pragma unroll
  for (int kc = 0; kc < 4; ++kc) {
    short8 af = *(const short8*)&xs[w * 16 + m][kc * 32 + q * 8];
#pragma unroll
    for (int nt = 0; nt < 4; ++nt) {
      short8 bfr = *(const short8*)&wt[nt * 16 + m][kc * 32 + q * 8];
      acc[nt] = __builtin_amdgcn_mfma_f32_16x16x32_bf16(af, bfr, acc[nt], 0, 0, 0);
    }
  }

#pragma unroll
  for (int nt = 0; nt < 4; ++nt)
#pragma unroll
    for (int r = 0; r < 4; ++r)
      sh[w * 16 + q * 4 + r][nt * 16 + m] = f2b(acc[nt][r]);
  __syncthreads();

  {
    int n = t >> 2, hd = t & 3;
    int gn = nb + n;
    if (gn < n_nodes) {
      float es = 0.f, ed = 0.f;
#pragma unroll
      for (int f = 0; f < OUT_FEAT; ++f) {
        float hv = b2f(sh[n][hd * 16 + f]);
        es = fmaf(hv, a[hd * 2 * OUT_FEAT + f], es);
        ed = fmaf(hv, a[hd * 2 * OUT_FEAT + OUT_FEAT + f], ed);
      }
      e_src[gn * N_HEADS + hd] = es;
      e_dst[gn * N_HEADS + hd] = ed;
    }
  }

  for (int i = t; i < 64 * 16; i += 256) {
    int n = i >> 4, c4 = (i & 15) * 4;
    int gn = nb + n;
    if (gn < n_nodes) {
      ushort4 v;
      v.x = sh[n][c4 + 0]; v.y = sh[n][c4 + 1];
      v.z = sh[n][c4 + 2]; v.w = sh[n][c4 + 3];
      *(ushort4*)(h16 + (size_t)gn * HF + c4) = v;
    }
  }
}

// ---------------------------------------------------------------------------
// Bucket histogram: per-block LDS histogram -> bh[block][bucket]. No atomics
// to global. Chunk mapping MUST match k_part.
// ---------------------------------------------------------------------------
__global__ __launch_bounds__(256) void k_bh(
    const int* __restrict__ dst, int* __restrict__ bh,
    int nbuck, int chunk, int n_edges) {
  __shared__ int h[NBUCK_MAX];
  int t = threadIdx.x;
  for (int k = t; k < NBUCK_MAX; k += 256) h[k] = 0;
  __syncthreads();
  int beg = blockIdx.x * chunk;
  int end = min(beg + chunk, n_edges);
  for (int e = beg + t; e < end; e += 256)
    atomicAdd(&h[dst[e] >> BSHIFT], 1);
  __syncthreads();
  for (int k = t; k < nbuck; k += 256)
    bh[blockIdx.x * nbuck + k] = h[k];
}

// ---------------------------------------------------------------------------
// Scan: column-sum bh -> bucket totals -> exclusive scan -> per-(block,bucket)
// bases gbase[b][k] and bucket_base[k]. Single block, deterministic.
// ---------------------------------------------------------------------------
__global__ __launch_bounds__(256) void k_scan(
    const int* __restrict__ bh, int* __restrict__ gbase,
    int* __restrict__ bucket_base, int nbuck, int npb, int n_edges) {
  __shared__ int tot[NBUCK_MAX];
  int t = threadIdx.x;
  for (int k = t; k < NBUCK_MAX; k += 256) {
    int s = 0;
    if (k < nbuck)
      for (int b = 0; b < npb; ++b) s += bh[b * nbuck + k];
    tot[k] = s;
  }
  __syncthreads();
  // Inclusive Hillis-Steele over NBUCK_MAX=512 slots, 2 slots/thread.
  for (int off = 1; off < NBUCK_MAX; off <<= 1) {
    int v0 = (t >= off) ? tot[t - off] : 0;
    int v1 = (t + 256 >= off) ? tot[t + 256 - off] : 0;
    __syncthreads();
    tot[t] += v0;
    tot[t + 256] += v1;
    __syncthreads();
  }
  for (int k = t; k < nbuck; k += 256) {
    int run = (k == 0) ? 0 : tot[k - 1];
    bucket_base[k] = run;
    for (int b = 0; b < npb; ++b) {
      gbase[b * nbuck + k] = run;
      run += bh[b * nbuck + k];
    }
  }
  if (t == 0) bucket_base[nbuck] = n_edges;
}

// ---------------------------------------------------------------------------
// Partition: softmax alpha per edge, then scatter one 16B record
// {src, d&127, alpha_lo, alpha_hi} to its bucket slot. LDS cursor atomics
// only (pre-reserved per-block ranges from gbase) — ZERO global atomics.
// ---------------------------------------------------------------------------
__global__ __launch_bounds__(256) void k_part(
    const int* __restrict__ src, const int* __restrict__ dst,
    const float* __restrict__ e_src, const float* __restrict__ e_dst,
    const int* __restrict__ gbase, uint4* __restrict__ recs,
    int nbuck, int chunk, int n_edges) {
  __shared__ int cur[NBUCK_MAX];
  int t = threadIdx.x;
  for (int k = t; k < nbuck; k += 256)
    cur[k] = gbase[blockIdx.x * nbuck + k];
  __syncthreads();
  int beg = blockIdx.x * chunk;
  int end = min(beg + chunk, n_edges);
  for (int e = beg + t; e < end; e += 256) {
    int s = src[e], d = dst[e];
    float4 es = ((const float4*)e_src)[s];
    float4 ed = ((const float4*)e_dst)[d];
    float v0 = es.x + ed.x, v1 = es.y + ed.y, v2 = es.z + ed.z, v3 = es.w + ed.w;
    v0 = (v0 > 0.f) ? v0 : NEG_SLOPE * v0;
    v1 = (v1 > 0.f) ? v1 : NEG_SLOPE * v1;
    v2 = (v2 > 0.f) ? v2 : NEG_SLOPE * v2;
    v3 = (v3 > 0.f) ? v3 : NEG_SLOPE * v3;
    float m = fmaxf(fmaxf(v0, v1), fmaxf(v2, v3));
    float e0 = __expf(v0 - m), e1 = __expf(v1 - m);
    float e2 = __expf(v2 - m), e3 = __expf(v3 - m);
    float inv = 1.f / (e0 + e1 + e2 + e3);
    unsigned lo = (unsigned)f2b(e0 * inv) | ((unsigned)f2b(e1 * inv) << 16);
    unsigned hi = (unsigned)f2b(e2 * inv) | ((unsigned)f2b(e3 * inv) << 16);
    int pos = atomicAdd(&cur[d >> BSHIFT], 1);
    recs[pos] = make_uint4((unsigned)s, (unsigned)(d & (BNODES - 1)), lo, hi);
  }
}

// ---------------------------------------------------------------------------
// Gather: one block per bucket (128 dst nodes), fp32 accumulation in a 32KB
// LDS tile via ds_add_f32 (LDS atomics). Lane = feature. 8 waves stride the
// bucket's edge list; records are broadcast reads, h16 rows are coalesced.
// ---------------------------------------------------------------------------
__global__ __launch_bounds__(512) void k_gather2(
    const uint4* __restrict__ recs, const int* __restrict__ bucket_base,
    const unsigned short* __restrict__ h16, float* __restrict__ out,
    int n_nodes) {
  __shared__ float acc[BNODES * HF];  // 32 KB
  int t = threadIdx.x;
  for (int i = t; i < BNODES * HF; i += 512) acc[i] = 0.f;
  __syncthreads();
  int beg = bucket_base[blockIdx.x];
  int end = bucket_base[blockIdx.x + 1];
  int nloc = end - beg;
  const uint4* rb = recs + beg;
  int w = t >> 6, c = t & 63;
  unsigned sel = (unsigned)(c >> 4);

  int jj = w;
  for (; jj + 24 < nloc; jj += 32) {
    uint4 r0 = rb[jj];
    uint4 r1 = rb[jj + 8];
    uint4 r2 = rb[jj + 16];
    uint4 r3 = rb[jj + 24];
    float h0 = b2f(h16[(size_t)r0.x * HF + c]);
    float h1 = b2f(h16[(size_t)r1.x * HF + c]);
    float h2 = b2f(h16[(size_t)r2.x * HF + c]);
    float h3 = b2f(h16[(size_t)r3.x * HF + c]);
    atomicAdd(&acc[(r0.y << 6) + c], alpha_lane(r0.z, r0.w, sel) * h0);
    atomicAdd(&acc[(r1.y << 6) + c], alpha_lane(r1.z, r1.w, sel) * h1);
    atomicAdd(&acc[(r2.y << 6) + c], alpha_lane(r2.z, r2.w, sel) * h2);
    atomicAdd(&acc[(r3.y << 6) + c], alpha_lane(r3.z, r3.w, sel) * h3);
  }
  for (; jj < nloc; jj += 8) {
    uint4 r = rb[jj];
    float hv = b2f(h16[(size_t)r.x * HF + c]);
    atomicAdd(&acc[(r.y << 6) + c], alpha_lane(r.z, r.w, sel) * hv);
  }
  __syncthreads();

  const float4* acc4 = (const float4*)acc;
  float4* out4 = (float4*)out;
  int base_node = blockIdx.x << BSHIFT;
  for (int i = t; i < BNODES * (HF / 4); i += 512) {
    int node = base_node + (i >> 4);
    if (node < n_nodes) out4[(size_t)node * (HF / 4) + (i & 15)] = acc4[i];
  }
}

extern "C" void kernel_launch(void* const* d_in, const int* in_sizes, int n_in,
                              void* d_out, int out_size, void* d_ws, size_t ws_size,
                              hipStream_t stream) {
  const float* x = (const float*)d_in[0];
  const int* ei = (const int*)d_in[1];
  const float* W = (const float*)d_in[2];
  const float* a = (const float*)d_in[3];
  float* out = (float*)d_out;

  const int n_nodes = in_sizes[0] / IN_FEAT;   // 50000
  const int n_edges = in_sizes[1] / 2;         // 800000
  const int* src = ei;
  const int* dst = ei + n_edges;

  const int nbuck = (n_nodes + BNODES - 1) >> BSHIFT;     // 391 (<= NBUCK_MAX)
  const int chunk = (n_edges + NPB - 1) / NPB;            // 3125

  char* ws = (char*)d_ws;
  size_t off = 0;
  uint4* recs = (uint4*)(ws + off);        off += (size_t)n_edges * 16;           // 12.8 MB
  unsigned short* h16 = (unsigned short*)(ws + off); off += (size_t)n_nodes * HF * 2; // 6.4 MB
  float* e_src = (float*)(ws + off);       off += (size_t)n_nodes * N_HEADS * 4;  // 0.8 MB
  float* e_dst = (float*)(ws + off);       off += (size_t)n_nodes * N_HEADS * 4;  // 0.8 MB
  int* bh = (int*)(ws + off);              off += (size_t)NPB * nbuck * 4;        // 0.4 MB
  int* gbase = (int*)(ws + off);           off += (size_t)NPB * nbuck * 4;        // 0.4 MB
  int* bucket_base = (int*)(ws + off);     off += (size_t)(nbuck + 1) * 4;

  // No memsets needed: bh/gbase/bucket_base/recs are fully written; gather
  // accumulator lives in LDS. Zero global atomics anywhere in the pipeline.
  k_gemm<<<(n_nodes + 63) / 64, 256, 0, stream>>>(x, W, a, h16, e_src, e_dst, n_nodes);
  k_bh<<<NPB, 256, 0, stream>>>(dst, bh, nbuck, chunk, n_edges);
  k_scan<<<1, 256, 0, stream>>>(bh, gbase, bucket_base, nbuck, NPB, n_edges);
  k_part<<<NPB, 256, 0, stream>>>(src, dst, e_src, e_dst, gbase, recs, nbuck, chunk, n_edges);
  k_gather2<<<nbuck, 512, 0, stream>>>(recs, bucket_base, h16, out, n_nodes);
}

// Round 3
// 165.606 us; speedup vs baseline: 3.8401x; 3.8401x over previous
//
#include <hip/hip_runtime.h>
#include <hip/hip_bf16.h>

#define IN_FEAT 128
#define N_HEADS 4
#define OUT_FEAT 16
#define HF 64  // N_HEADS * OUT_FEAT
#define NEG_SLOPE 0.2f

#define BSHIFT 7                 // 128 nodes per bucket
#define BNODES 128
#define NBUCK_MAX 512            // >= ceil(50000/128)=391
#define NPB 512                  // edge-chunk blocks for k_bh / k_part

typedef __hip_bfloat16 bf16;
typedef __attribute__((ext_vector_type(8))) short short8;
typedef __attribute__((ext_vector_type(4))) float f32x4;

__device__ inline unsigned short f2b(float f) {
  bf16 b = __float2bfloat16(f);
  return *(unsigned short*)&b;
}
__device__ inline float b2f(unsigned short u) {
  return __uint_as_float((unsigned)u << 16);
}

// ---------------------------------------------------------------------------
// Kernel 1: h = x @ W via bf16 MFMA (pure — zero atomics).
// Block = 256 thr = 4 waves = 64 nodes; 16 mfma_f32_16x16x32_bf16 per wave.
// ---------------------------------------------------------------------------
__global__ __launch_bounds__(256) void k_gemm(
    const float* __restrict__ x, const float* __restrict__ W,
    const float* __restrict__ a, unsigned short* __restrict__ h16,
    float* __restrict__ e_src, float* __restrict__ e_dst, int n_nodes) {
  __shared__ unsigned short xs[64][136];
  __shared__ unsigned short wt[64][136];
  __shared__ unsigned short sh[64][68];
  const int t = threadIdx.x;
  const int nb = blockIdx.x * 64;
  const int lane = t & 63;
  const int w = t >> 6;

  const float4* x4 = (const float4*)x;
  for (int i = t; i < 64 * 32; i += 256) {
    int n = i >> 5, k4 = i & 31;
    int gn = nb + n;
    float4 v = (gn < n_nodes) ? x4[(size_t)gn * 32 + k4]
                              : make_float4(0.f, 0.f, 0.f, 0.f);
    ushort4 u;
    u.x = f2b(v.x); u.y = f2b(v.y); u.z = f2b(v.z); u.w = f2b(v.w);
    *(ushort4*)&xs[n][k4 * 4] = u;
  }
  for (int i = t; i < IN_FEAT * HF; i += 256) {
    int k = i >> 6, c = i & 63;
    wt[c][k] = f2b(W[i]);
  }
  __syncthreads();

  const int m = lane & 15;
  const int q = lane >> 4;
  f32x4 acc[4];
#pragma unroll
  for (int nt = 0; nt < 4; ++nt) acc[nt] = (f32x4){0.f, 0.f, 0.f, 0.f};

#pragma unroll
  for (int kc = 0; kc < 4; ++kc) {
    short8 af = *(const short8*)&xs[w * 16 + m][kc * 32 + q * 8];
#pragma unroll
    for (int nt = 0; nt < 4; ++nt) {
      short8 bfr = *(const short8*)&wt[nt * 16 + m][kc * 32 + q * 8];
      acc[nt] = __builtin_amdgcn_mfma_f32_16x16x32_bf16(af, bfr, acc[nt], 0, 0, 0);
    }
  }

#pragma unroll
  for (int nt = 0; nt < 4; ++nt)
#pragma unroll
    for (int r = 0; r < 4; ++r)
      sh[w * 16 + q * 4 + r][nt * 16 + m] = f2b(acc[nt][r]);
  __syncthreads();

  {
    int n = t >> 2, hd = t & 3;
    int gn = nb + n;
    if (gn < n_nodes) {
      float es = 0.f, ed = 0.f;
#pragma unroll
      for (int f = 0; f < OUT_FEAT; ++f) {
        float hv = b2f(sh[n][hd * 16 + f]);
        es = fmaf(hv, a[hd * 2 * OUT_FEAT + f], es);
        ed = fmaf(hv, a[hd * 2 * OUT_FEAT + OUT_FEAT + f], ed);
      }
      e_src[gn * N_HEADS + hd] = es;
      e_dst[gn * N_HEADS + hd] = ed;
    }
  }

  for (int i = t; i < 64 * 16; i += 256) {
    int n = i >> 4, c4 = (i & 15) * 4;
    int gn = nb + n;
    if (gn < n_nodes) {
      ushort4 v;
      v.x = sh[n][c4 + 0]; v.y = sh[n][c4 + 1];
      v.z = sh[n][c4 + 2]; v.w = sh[n][c4 + 3];
      *(ushort4*)(h16 + (size_t)gn * HF + c4) = v;
    }
  }
}

// ---------------------------------------------------------------------------
// Bucket histogram: per-block LDS histogram -> bh[bucket][block]. LDS atomics
// only. Chunk mapping MUST match k_part.
// ---------------------------------------------------------------------------
__global__ __launch_bounds__(256) void k_bh(
    const int* __restrict__ dst, int* __restrict__ bh,
    int nbuck, int chunk, int n_edges) {
  __shared__ int h[NBUCK_MAX];
  int t = threadIdx.x;
  for (int k = t; k < NBUCK_MAX; k += 256) h[k] = 0;
  __syncthreads();
  int beg = blockIdx.x * chunk;
  int end = min(beg + chunk, n_edges);
  for (int e = beg + t; e < end; e += 256)
    atomicAdd(&h[dst[e] >> BSHIFT], 1);
  __syncthreads();
  for (int k = t; k < nbuck; k += 256)
    bh[(size_t)k * NPB + blockIdx.x] = h[k];
}

// ---------------------------------------------------------------------------
// scanA: one block per bucket; parallel exclusive scan of bh[k][0..NPB) over
// the NPB edge-chunk blocks -> sbase[k][b], and bucket total -> tot[k].
// ---------------------------------------------------------------------------
__global__ __launch_bounds__(NPB) void k_scanA(
    const int* __restrict__ bh, int* __restrict__ sbase, int* __restrict__ tot) {
  __shared__ int s[NPB];
  int t = threadIdx.x, k = blockIdx.x;
  int v = bh[(size_t)k * NPB + t];
  s[t] = v;
  __syncthreads();
  for (int off = 1; off < NPB; off <<= 1) {
    int u = (t >= off) ? s[t - off] : 0;
    __syncthreads();
    s[t] += u;
    __syncthreads();
  }
  sbase[(size_t)k * NPB + t] = s[t] - v;
  if (t == NPB - 1) tot[k] = s[t];
}

// ---------------------------------------------------------------------------
// scanB: single block; exclusive scan of bucket totals -> bucket_base.
// ---------------------------------------------------------------------------
__global__ __launch_bounds__(NPB) void k_scanB(
    const int* __restrict__ tot, int* __restrict__ bucket_base,
    int* __restrict__ offsets, int nbuck, int n_edges, int n_nodes) {
  __shared__ int s[NPB];
  int t = threadIdx.x;
  int v = (t < nbuck) ? tot[t] : 0;
  s[t] = v;
  __syncthreads();
  for (int off = 1; off < NPB; off <<= 1) {
    int u = (t >= off) ? s[t - off] : 0;
    __syncthreads();
    s[t] += u;
    __syncthreads();
  }
  if (t < nbuck) bucket_base[t] = s[t] - v;
  if (t == 0) {
    bucket_base[nbuck] = n_edges;
    offsets[n_nodes] = n_edges;
  }
}

// ---------------------------------------------------------------------------
// Partition: softmax alpha per edge, scatter one 16B record
// {src, d&127, alpha_lo, alpha_hi} to its bucket-exact slot. LDS cursors
// pre-reserved from bucket_base + sbase — ZERO global atomics.
// ---------------------------------------------------------------------------
__global__ __launch_bounds__(256) void k_part(
    const int* __restrict__ src, const int* __restrict__ dst,
    const float* __restrict__ e_src, const float* __restrict__ e_dst,
    const int* __restrict__ bucket_base, const int* __restrict__ sbase,
    uint4* __restrict__ recs, int nbuck, int chunk, int n_edges) {
  __shared__ int cur[NBUCK_MAX];
  int t = threadIdx.x;
  for (int k = t; k < nbuck; k += 256)
    cur[k] = bucket_base[k] + sbase[(size_t)k * NPB + blockIdx.x];
  __syncthreads();
  int beg = blockIdx.x * chunk;
  int end = min(beg + chunk, n_edges);
  for (int e = beg + t; e < end; e += 256) {
    int s = src[e], d = dst[e];
    float4 es = ((const float4*)e_src)[s];
    float4 ed = ((const float4*)e_dst)[d];
    float v0 = es.x + ed.x, v1 = es.y + ed.y, v2 = es.z + ed.z, v3 = es.w + ed.w;
    v0 = (v0 > 0.f) ? v0 : NEG_SLOPE * v0;
    v1 = (v1 > 0.f) ? v1 : NEG_SLOPE * v1;
    v2 = (v2 > 0.f) ? v2 : NEG_SLOPE * v2;
    v3 = (v3 > 0.f) ? v3 : NEG_SLOPE * v3;
    float m = fmaxf(fmaxf(v0, v1), fmaxf(v2, v3));
    float e0 = __expf(v0 - m), e1 = __expf(v1 - m);
    float e2 = __expf(v2 - m), e3 = __expf(v3 - m);
    float inv = 1.f / (e0 + e1 + e2 + e3);
    unsigned lo = (unsigned)f2b(e0 * inv) | ((unsigned)f2b(e1 * inv) << 16);
    unsigned hi = (unsigned)f2b(e2 * inv) | ((unsigned)f2b(e3 * inv) << 16);
    int pos = atomicAdd(&cur[d >> BSHIFT], 1);
    recs[pos] = make_uint4((unsigned)s, (unsigned)(d & (BNODES - 1)), lo, hi);
  }
}

// ---------------------------------------------------------------------------
// Within-bucket counting sort by 7-bit local dst: LDS 128-bin histogram +
// scan + scatter into sorted_src/alpha8; also emits per-node offsets.
// All scattered writes land in an L2-resident window. LDS atomics only.
// ---------------------------------------------------------------------------
__global__ __launch_bounds__(512) void k_sort(
    const uint4* __restrict__ recs, const int* __restrict__ bucket_base,
    int* __restrict__ sorted_src, unsigned long long* __restrict__ alpha8,
    int* __restrict__ offsets, int nbuck, int n_nodes) {
  __shared__ int hist[BNODES];
  __shared__ int cur[BNODES];
  int t = threadIdx.x, k = blockIdx.x;
  int beg = bucket_base[k];
  int n = bucket_base[k + 1] - beg;
  if (t < BNODES) hist[t] = 0;
  __syncthreads();
  for (int j = t; j < n; j += 512)
    atomicAdd(&hist[recs[beg + j].y], 1);
  __syncthreads();
  int v = (t < BNODES) ? hist[t] : 0;
  for (int off = 1; off < BNODES; off <<= 1) {
    int u = (t < BNODES && t >= off) ? hist[t - off] : 0;
    __syncthreads();
    if (t < BNODES) hist[t] += u;
    __syncthreads();
  }
  if (t < BNODES) {
    int pos = beg + hist[t] - v;  // exclusive
    cur[t] = pos;
    int node = (k << BSHIFT) + t;
    if (node < n_nodes) offsets[node] = pos;
  }
  __syncthreads();
  for (int j = t; j < n; j += 512) {
    uint4 r = recs[beg + j];
    int p = atomicAdd(&cur[r.y], 1);
    sorted_src[p] = (int)r.x;
    alpha8[p] = (unsigned long long)r.z | ((unsigned long long)r.w << 32);
  }
}

// ---------------------------------------------------------------------------
// Gather: one wave per dst node, lane = feature (round-1 proven kernel).
// ---------------------------------------------------------------------------
__global__ __launch_bounds__(256) void k_gather(
    const int* __restrict__ sorted_src,
    const unsigned long long* __restrict__ alpha8,
    const int* __restrict__ offsets, const unsigned short* __restrict__ h16,
    float* __restrict__ out, int n_nodes) {
  int gid = blockIdx.x * 256 + threadIdx.x;
  int d = gid >> 6;
  int c = gid & 63;
  if (d >= n_nodes) return;
  int beg = offsets[d];
  int end = offsets[d + 1];
  unsigned shamt = (unsigned)(c >> 4) * 16;
  float acc = 0.f;
  int j = beg;
  for (; j + 8 <= end; j += 8) {
    int s[8];
    unsigned long long au[8];
    float hv[8];
#pragma unroll
    for (int k = 0; k < 8; ++k) s[k] = sorted_src[j + k];
#pragma unroll
    for (int k = 0; k < 8; ++k) au[k] = alpha8[j + k];
#pragma unroll
    for (int k = 0; k < 8; ++k) hv[k] = b2f(h16[(size_t)s[k] * HF + c]);
#pragma unroll
    for (int k = 0; k < 8; ++k) {
      float al = __uint_as_float(((unsigned)(au[k] >> shamt)) << 16);
      acc = fmaf(al, hv[k], acc);
    }
  }
  for (; j < end; ++j) {
    int s = sorted_src[j];
    unsigned long long au = alpha8[j];
    float al = __uint_as_float(((unsigned)(au >> shamt)) << 16);
    acc = fmaf(al, b2f(h16[(size_t)s * HF + c]), acc);
  }
  out[(size_t)d * HF + c] = acc;
}

extern "C" void kernel_launch(void* const* d_in, const int* in_sizes, int n_in,
                              void* d_out, int out_size, void* d_ws, size_t ws_size,
                              hipStream_t stream) {
  const float* x = (const float*)d_in[0];
  const int* ei = (const int*)d_in[1];
  const float* W = (const float*)d_in[2];
  const float* a = (const float*)d_in[3];
  float* out = (float*)d_out;

  const int n_nodes = in_sizes[0] / IN_FEAT;   // 50000
  const int n_edges = in_sizes[1] / 2;         // 800000
  const int* src = ei;
  const int* dst = ei + n_edges;

  const int nbuck = (n_nodes + BNODES - 1) >> BSHIFT;     // 391 (<= NBUCK_MAX)
  const int chunk = (n_edges + NPB - 1) / NPB;            // 1563

  char* ws = (char*)d_ws;
  size_t off = 0;
  uint4* recs = (uint4*)(ws + off);        off += (size_t)n_edges * 16;           // 12.8 MB
  unsigned long long* alpha8 = (unsigned long long*)(ws + off); off += (size_t)n_edges * 8; // 6.4 MB
  unsigned short* h16 = (unsigned short*)(ws + off); off += (size_t)n_nodes * HF * 2; // 6.4 MB
  int* sorted_src = (int*)(ws + off);      off += (size_t)n_edges * 4;            // 3.2 MB
  float* e_src = (float*)(ws + off);       off += (size_t)n_nodes * N_HEADS * 4;  // 0.8 MB
  float* e_dst = (float*)(ws + off);       off += (size_t)n_nodes * N_HEADS * 4;  // 0.8 MB
  int* bh = (int*)(ws + off);              off += (size_t)NBUCK_MAX * NPB * 4;    // 1.0 MB
  int* sbase = (int*)(ws + off);           off += (size_t)NBUCK_MAX * NPB * 4;    // 1.0 MB
  int* tot = (int*)(ws + off);             off += (size_t)NBUCK_MAX * 4;
  int* bucket_base = (int*)(ws + off);     off += (size_t)(NBUCK_MAX + 1) * 4;
  int* offsets = (int*)(ws + off);         off += ((size_t)n_nodes + 16) * 4;

  // Zero global atomics anywhere; no memsets needed (all buffers fully
  // written before read: bh by k_bh, sbase/tot by scanA, bucket_base/offsets
  // terminal entries by scanB, per-node offsets by k_sort).
  k_gemm<<<(n_nodes + 63) / 64, 256, 0, stream>>>(x, W, a, h16, e_src, e_dst, n_nodes);
  k_bh<<<NPB, 256, 0, stream>>>(dst, bh, nbuck, chunk, n_edges);
  k_scanA<<<nbuck, NPB, 0, stream>>>(bh, sbase, tot);
  k_scanB<<<1, NPB, 0, stream>>>(tot, bucket_base, offsets, nbuck, n_edges, n_nodes);
  k_part<<<NPB, 256, 0, stream>>>(src, dst, e_src, e_dst, bucket_base, sbase, recs, nbuck, chunk, n_edges);
  k_sort<<<nbuck, 512, 0, stream>>>(recs, bucket_base, sorted_src, alpha8, offsets, nbuck, n_nodes);
  k_gather<<<((size_t)n_nodes * 64 + 255) / 256, 256, 0, stream>>>(
      sorted_src, alpha8, offsets, h16, out, n_nodes);
}